// Round 1
// baseline (9834.647 us; speedup 1.0000x reference)
//
#include <hip/hip_runtime.h>

#define N_NODES 50000
#define N_EDGES 500000
#define N_REL   50

// workspace layout (floats)
#define CNT_OFF 0
#define S1_OFF  (N_NODES)                    // 50'000
#define S2_OFF  (S1_OFF + N_NODES*16)        // 850'000
#define ZERO_FLOATS (S2_OFF + N_NODES*64)    // 4'050'000  (cnt+s1+s2 must be zeroed)
#define H1_OFF  ZERO_FLOATS                  // 4'050'000
#define H2_OFF  (H1_OFF + N_NODES*64)        // 7'250'000
// total = 13'650'000 floats = 54.6 MB

__global__ __launch_bounds__(256) void k_scatter1(
    const float* __restrict__ x, const int* __restrict__ src,
    const int* __restrict__ dst, float* __restrict__ s1, float* __restrict__ cnt)
{
    int t = blockIdx.x * blockDim.x + threadIdx.x;
    if (t >= N_EDGES * 16) return;
    int e = t >> 4, f = t & 15;
    int s = src[e], d = dst[e];
    atomicAdd(&s1[d * 16 + f], x[s * 16 + f]);
    if (f == 0) atomicAdd(&cnt[d], 1.0f);
}

__global__ __launch_bounds__(64) void k_sage1(
    const float* __restrict__ x, const float* __restrict__ s1,
    const float* __restrict__ cnt,
    const float* __restrict__ w1_l, const float* __restrict__ b1,
    const float* __restrict__ w1_r, float* __restrict__ h1)
{
    int i = blockIdx.x;
    int o = threadIdx.x;               // 0..63
    __shared__ float xm[32];           // [0,16) = x row, [16,32) = mean row
    if (o < 16) {
        xm[o] = x[i * 16 + o];
    } else if (o < 32) {
        float c = cnt[i];
        c = c < 1.0f ? 1.0f : c;
        xm[o] = s1[i * 16 + (o - 16)] / c;
    }
    __syncthreads();
    float acc = b1[o];
#pragma unroll
    for (int f = 0; f < 16; ++f) {
        acc += xm[16 + f] * w1_l[o * 16 + f];   // mean @ w1_l.T
        acc += xm[f]      * w1_r[o * 16 + f];   // x    @ w1_r.T
    }
    h1[i * 64 + o] = acc > 0.0f ? acc : 0.0f;
}

__global__ __launch_bounds__(256) void k_scatter2(
    const float* __restrict__ h1, const int* __restrict__ src,
    const int* __restrict__ dst, float* __restrict__ s2)
{
    long long t = (long long)blockIdx.x * blockDim.x + threadIdx.x;
    if (t >= (long long)N_EDGES * 64) return;
    int e = (int)(t >> 6), f = (int)(t & 63);
    atomicAdd(&s2[(long long)dst[e] * 64 + f], h1[(long long)src[e] * 64 + f]);
}

__global__ __launch_bounds__(128) void k_sage2(
    const float* __restrict__ h1, const float* __restrict__ s2,
    const float* __restrict__ cnt,
    const float* __restrict__ w2_l, const float* __restrict__ b2,
    const float* __restrict__ w2_r, float* __restrict__ h2)
{
    int i = blockIdx.x;
    int o = threadIdx.x;               // 0..127
    __shared__ float hm[128];          // [0,64) = h1 row, [64,128) = mean row
    if (o < 64) {
        hm[o] = h1[i * 64 + o];
    } else {
        float c = cnt[i];
        c = c < 1.0f ? 1.0f : c;
        hm[o] = s2[i * 64 + (o - 64)] / c;
    }
    __syncthreads();
    float acc = b2[o];
#pragma unroll 16
    for (int f = 0; f < 64; ++f) {
        acc += hm[64 + f] * w2_l[o * 64 + f];
        acc += hm[f]      * w2_r[o * 64 + f];
    }
    h2[i * 128 + o] = acc > 0.0f ? acc : 0.0f;
}

// one wave per edge; per-wave LDS activation buffer
//   feat [0,256)  a1 [256,384)  a2 [384,448)  a3 [448,480)
//   a4 [480,496)  a5 [496,504)  a6 [504,508)
__global__ __launch_bounds__(256) void k_edge_mlp(
    const float* __restrict__ h2, const int* __restrict__ src,
    const int* __restrict__ dst, const int* __restrict__ y,
    const float* __restrict__ ow1, const float* __restrict__ ob1,
    const float* __restrict__ ow2, const float* __restrict__ ob2,
    const float* __restrict__ ow3, const float* __restrict__ ob3,
    const float* __restrict__ ow4, const float* __restrict__ ob4,
    const float* __restrict__ rw1, const float* __restrict__ rb1,
    const float* __restrict__ rw2, const float* __restrict__ rb2,
    const float* __restrict__ rw3, const float* __restrict__ rb3,
    float* __restrict__ out)
{
    __shared__ float sbuf[4 * 512];
    int wid  = threadIdx.x >> 6;
    int lane = threadIdx.x & 63;
    int e    = blockIdx.x * 4 + wid;
    float* B = sbuf + wid * 512;
    bool ok  = (e < N_EDGES);

    if (ok) {
        int s = src[e], d = dst[e];
        B[lane]        = h2[(long long)s * 128 + lane];
        B[64 + lane]   = h2[(long long)s * 128 + 64 + lane];
        B[128 + lane]  = h2[(long long)d * 128 + lane];
        B[192 + lane]  = h2[(long long)d * 128 + 64 + lane];
    }
    __syncthreads();

    // L1: 256 -> 128 (relu); each lane computes outputs lane and lane+64
    if (ok) {
        float a0 = ob1[lane], a1 = ob1[lane + 64];
        const float* w0 = ow1 + (long long)lane * 256;
        const float* w1 = ow1 + (long long)(lane + 64) * 256;
        for (int f = 0; f < 256; ++f) {
            float v = B[f];
            a0 += v * w0[f];
            a1 += v * w1[f];
        }
        B[256 + lane]      = a0 > 0.0f ? a0 : 0.0f;
        B[256 + 64 + lane] = a1 > 0.0f ? a1 : 0.0f;
    }
    __syncthreads();

    // L2: 128 -> 64 (relu)
    if (ok) {
        float a = ob2[lane];
        const float* w = ow2 + (long long)lane * 128;
        for (int f = 0; f < 128; ++f) a += B[256 + f] * w[f];
        B[384 + lane] = a > 0.0f ? a : 0.0f;
    }
    __syncthreads();

    // L3: 64 -> 32 (relu)
    if (ok && lane < 32) {
        float a = ob3[lane];
        const float* w = ow3 + lane * 64;
        for (int f = 0; f < 64; ++f) a += B[384 + f] * w[f];
        B[448 + lane] = a > 0.0f ? a : 0.0f;
    }
    __syncthreads();

    // L4: 32 -> 16 (NO relu)
    if (ok && lane < 16) {
        float a = ob4[lane];
        const float* w = ow4 + lane * 32;
        for (int f = 0; f < 32; ++f) a += B[448 + f] * w[f];
        B[480 + lane] = a;
    }
    __syncthreads();

    // rf1: 16 -> 8 (relu)
    if (ok && lane < 8) {
        float a = rb1[lane];
        const float* w = rw1 + lane * 16;
        for (int f = 0; f < 16; ++f) a += B[480 + f] * w[f];
        B[496 + lane] = a > 0.0f ? a : 0.0f;
    }
    __syncthreads();

    // rf2: 8 -> 4 (relu)
    if (ok && lane < 4) {
        float a = rb2[lane];
        const float* w = rw2 + lane * 8;
        for (int f = 0; f < 8; ++f) a += B[496 + f] * w[f];
        B[504 + lane] = a > 0.0f ? a : 0.0f;
    }
    __syncthreads();

    // rf3: 4 -> 50 (no relu), write r; lane 63 copies y as float
    if (ok) {
        if (lane < N_REL) {
            float a = rb3[lane];
            const float* w = rw3 + lane * 4;
#pragma unroll
            for (int f = 0; f < 4; ++f) a += B[504 + f] * w[f];
            out[(long long)e * N_REL + lane] = a;
        }
        if (lane == 63) {
            out[(long long)N_EDGES * N_REL + e] = (float)y[e];
        }
    }
}

extern "C" void kernel_launch(void* const* d_in, const int* in_sizes, int n_in,
                              void* d_out, int out_size, void* d_ws, size_t ws_size,
                              hipStream_t stream) {
    const float* x    = (const float*)d_in[0];
    const int*   ei   = (const int*)d_in[1];
    const int*   src  = ei;
    const int*   dst  = ei + N_EDGES;
    const int*   y    = (const int*)d_in[2];
    const float* w1_l = (const float*)d_in[3];
    const float* b1   = (const float*)d_in[4];
    const float* w1_r = (const float*)d_in[5];
    const float* w2_l = (const float*)d_in[6];
    const float* b2   = (const float*)d_in[7];
    const float* w2_r = (const float*)d_in[8];
    const float* ow1  = (const float*)d_in[9];
    const float* ob1  = (const float*)d_in[10];
    const float* ow2  = (const float*)d_in[11];
    const float* ob2  = (const float*)d_in[12];
    const float* ow3  = (const float*)d_in[13];
    const float* ob3  = (const float*)d_in[14];
    const float* ow4  = (const float*)d_in[15];
    const float* ob4  = (const float*)d_in[16];
    const float* rw1  = (const float*)d_in[17];
    const float* rb1  = (const float*)d_in[18];
    const float* rw2  = (const float*)d_in[19];
    const float* rb2  = (const float*)d_in[20];
    const float* rw3  = (const float*)d_in[21];
    const float* rb3  = (const float*)d_in[22];

    float* ws  = (float*)d_ws;
    float* cnt = ws + CNT_OFF;
    float* s1  = ws + S1_OFF;
    float* s2  = ws + S2_OFF;
    float* h1  = ws + H1_OFF;
    float* h2  = ws + H2_OFF;
    float* out = (float*)d_out;

    hipMemsetAsync(d_ws, 0, (size_t)ZERO_FLOATS * sizeof(float), stream);

    {   // scatter x + degree count
        int total = N_EDGES * 16;
        k_scatter1<<<(total + 255) / 256, 256, 0, stream>>>(x, src, dst, s1, cnt);
    }
    k_sage1<<<N_NODES, 64, 0, stream>>>(x, s1, cnt, w1_l, b1, w1_r, h1);
    {   // scatter h1
        long long total = (long long)N_EDGES * 64;
        k_scatter2<<<(int)((total + 255) / 256), 256, 0, stream>>>(h1, src, dst, s2);
    }
    k_sage2<<<N_NODES, 128, 0, stream>>>(h1, s2, cnt, w2_l, b2, w2_r, h2);

    k_edge_mlp<<<(N_EDGES + 3) / 4, 256, 0, stream>>>(
        h2, src, dst, y,
        ow1, ob1, ow2, ob2, ow3, ob3, ow4, ob4,
        rw1, rb1, rw2, rb2, rw3, rb3, out);
}

// Round 2
// 827.556 us; speedup vs baseline: 11.8840x; 11.8840x over previous
//
#include <hip/hip_runtime.h>
#include <hip/hip_bf16.h>

#define N_NODES 50000
#define N_EDGES 500000
#define N_REL   50
#define NTILES  ((N_EDGES + 63) / 64)   // 7813
#define PBLOCKS 512

// workspace layout (floats)
#define CNT_OFF 0
#define S1_OFF  (N_NODES)
#define S2_OFF  (S1_OFF + N_NODES*16)
#define ZERO_FLOATS (S2_OFF + N_NODES*64)
#define H1_OFF  ZERO_FLOATS
#define H2_OFF  (H1_OFF + N_NODES*64)

typedef short short8  __attribute__((ext_vector_type(8)));
typedef short short4v __attribute__((ext_vector_type(4)));
typedef float f32x4   __attribute__((ext_vector_type(4)));
typedef float f4      __attribute__((ext_vector_type(4)));

#define MFMA16(a,b,c) __builtin_amdgcn_mfma_f32_16x16x32_bf16((a),(b),(c),0,0,0)

__device__ __forceinline__ short f2bf(float x) {
    unsigned u = __float_as_uint(x);
    unsigned r = (u + 0x7fffu + ((u >> 16) & 1u)) >> 16;   // RNE
    return (short)r;
}

// load an 8-wide bf16 A-fragment row chunk from a row-major f32 weight matrix
__device__ __forceinline__ short8 load_wfrag(const float* __restrict__ W, int row, int K, int k) {
    const f4* p = (const f4*)(W + (size_t)row * K + k);
    f4 a = p[0], b = p[1];
    short8 r;
    r[0] = f2bf(a[0]); r[1] = f2bf(a[1]); r[2] = f2bf(a[2]); r[3] = f2bf(a[3]);
    r[4] = f2bf(b[0]); r[5] = f2bf(b[1]); r[6] = f2bf(b[2]); r[7] = f2bf(b[3]);
    return r;
}

// ---------------- graph kernels (unchanged from round 0) ----------------

__global__ __launch_bounds__(256) void k_scatter1(
    const float* __restrict__ x, const int* __restrict__ src,
    const int* __restrict__ dst, float* __restrict__ s1, float* __restrict__ cnt)
{
    int t = blockIdx.x * blockDim.x + threadIdx.x;
    if (t >= N_EDGES * 16) return;
    int e = t >> 4, f = t & 15;
    int s = src[e], d = dst[e];
    atomicAdd(&s1[d * 16 + f], x[s * 16 + f]);
    if (f == 0) atomicAdd(&cnt[d], 1.0f);
}

__global__ __launch_bounds__(64) void k_sage1(
    const float* __restrict__ x, const float* __restrict__ s1,
    const float* __restrict__ cnt,
    const float* __restrict__ w1_l, const float* __restrict__ b1,
    const float* __restrict__ w1_r, float* __restrict__ h1)
{
    int i = blockIdx.x;
    int o = threadIdx.x;
    __shared__ float xm[32];
    if (o < 16) {
        xm[o] = x[i * 16 + o];
    } else if (o < 32) {
        float c = cnt[i];
        c = c < 1.0f ? 1.0f : c;
        xm[o] = s1[i * 16 + (o - 16)] / c;
    }
    __syncthreads();
    float acc = b1[o];
#pragma unroll
    for (int f = 0; f < 16; ++f) {
        acc += xm[16 + f] * w1_l[o * 16 + f];
        acc += xm[f]      * w1_r[o * 16 + f];
    }
    h1[i * 64 + o] = acc > 0.0f ? acc : 0.0f;
}

__global__ __launch_bounds__(256) void k_scatter2(
    const float* __restrict__ h1, const int* __restrict__ src,
    const int* __restrict__ dst, float* __restrict__ s2)
{
    long long t = (long long)blockIdx.x * blockDim.x + threadIdx.x;
    if (t >= (long long)N_EDGES * 64) return;
    int e = (int)(t >> 6), f = (int)(t & 63);
    atomicAdd(&s2[(long long)dst[e] * 64 + f], h1[(long long)src[e] * 64 + f]);
}

__global__ __launch_bounds__(128) void k_sage2(
    const float* __restrict__ h1, const float* __restrict__ s2,
    const float* __restrict__ cnt,
    const float* __restrict__ w2_l, const float* __restrict__ b2,
    const float* __restrict__ w2_r, float* __restrict__ h2)
{
    int i = blockIdx.x;
    int o = threadIdx.x;
    __shared__ float hm[128];
    if (o < 64) {
        hm[o] = h1[i * 64 + o];
    } else {
        float c = cnt[i];
        c = c < 1.0f ? 1.0f : c;
        hm[o] = s2[i * 64 + (o - 64)] / c;
    }
    __syncthreads();
    float acc = b2[o];
#pragma unroll 16
    for (int f = 0; f < 64; ++f) {
        acc += hm[64 + f] * w2_l[o * 64 + f];
        acc += hm[f]      * w2_r[o * 64 + f];
    }
    h2[i * 128 + o] = acc > 0.0f ? acc : 0.0f;
}

// ---------------- fused edge MLP, MFMA, 64 edges / tile ----------------
// M = output features, N = edges (swapped-operand form):
//   D[out][edge] = sum_k W[out][k] * feat[edge][k]
// A-frag (W):   lane l -> row = l&15 (+16*mt), k = (l>>4)*8 + j
// B-frag (act): lane l -> col(edge) = l&15 (+16*nt), k = (l>>4)*8 + j
// D:            col(edge) = l&15, row(out) = (l>>4)*4 + r        [m89-verified]
//
// smallw layout (floats):
//  [0,128) ob1 | [128,192) ob2 | [192,224) ob3 | [224,240) ob4
//  [240,248) rb1 | [248,252) rb2 | [252,302) rb3
//  [302,430) rw1(8x16) | [430,462) rw2(4x8) | [462,662) rw3(50x4)
__global__ __launch_bounds__(256, 2) void k_edge_fused(
    const float* __restrict__ h2, const int* __restrict__ src,
    const int* __restrict__ dst, const int* __restrict__ y,
    const float* __restrict__ ow1, const float* __restrict__ ob1,
    const float* __restrict__ ow2, const float* __restrict__ ob2,
    const float* __restrict__ ow3, const float* __restrict__ ob3,
    const float* __restrict__ ow4, const float* __restrict__ ob4,
    const float* __restrict__ rw1, const float* __restrict__ rb1,
    const float* __restrict__ rw2, const float* __restrict__ rb2,
    const float* __restrict__ rw3, const float* __restrict__ rb3,
    float* __restrict__ out)
{
    __shared__ short feat[64 * 256];   // 32KB; dead after L1 -> aliased below
    __shared__ short act1[64 * 128];   // 16KB
    __shared__ float act4[64 * 17];    // padded stride 17 -> conflict-free tail reads
    __shared__ float act6[64 * 4];
    __shared__ float sw[662];

    short* act2 = feat;                // 64*64 shorts
    short* act3 = feat + 64 * 64;      // 64*32 shorts

    const int t    = threadIdx.x;
    const int w    = t >> 6;           // wave 0..3
    const int lane = t & 63;
    const int lr   = lane & 15;
    const int lg   = lane >> 4;

    // stage small weights/biases
    if (t < 128) sw[t]       = ob1[t];
    if (t < 64)  sw[128 + t] = ob2[t];
    if (t < 32)  sw[192 + t] = ob3[t];
    if (t < 16)  sw[224 + t] = ob4[t];
    if (t < 8)   sw[240 + t] = rb1[t];
    if (t < 4)   sw[248 + t] = rb2[t];
    if (t < 50)  sw[252 + t] = rb3[t];
    if (t < 128) sw[302 + t] = rw1[t];
    if (t < 32)  sw[430 + t] = rw2[t];
    if (t < 200) sw[462 + t] = rw3[t];

    // per-wave weight fragments in registers (held across all tiles)
    short8 w1f[2][8];                  // wave w owns out rows [w*32, w*32+32)
#pragma unroll
    for (int mt = 0; mt < 2; ++mt)
#pragma unroll
        for (int kt = 0; kt < 8; ++kt)
            w1f[mt][kt] = load_wfrag(ow1, w * 32 + mt * 16 + lr, 256, kt * 32 + lg * 8);

    short8 w2f[4];                     // wave w owns out rows [w*16, w*16+16)
#pragma unroll
    for (int kt = 0; kt < 4; ++kt)
        w2f[kt] = load_wfrag(ow2, w * 16 + lr, 128, kt * 32 + lg * 8);

    short8 w3f[2][2];                  // all 32 outs (every wave)
#pragma unroll
    for (int mt = 0; mt < 2; ++mt)
#pragma unroll
        for (int kt = 0; kt < 2; ++kt)
            w3f[mt][kt] = load_wfrag(ow3, mt * 16 + lr, 64, kt * 32 + lg * 8);

    short8 w4f = load_wfrag(ow4, lr, 32, lg * 8);

    for (int tile = blockIdx.x; tile < NTILES; tile += PBLOCKS) {
        const int base = tile * 64;

        // ---- stage feat tile: [64 edges][256] bf16, swizzled ----
        {
            int e    = t >> 2;
            int half = (t >> 1) & 1;            // 0 = src node, 1 = dst node
            int eg   = base + e;
            const float* np = nullptr;
            if (eg < N_EDGES) {
                int node = half ? dst[eg] : src[eg];
                np = h2 + (size_t)node * 128 + (t & 1) * 64;
            }
#pragma unroll
            for (int j = 0; j < 8; ++j) {
                short8 v;
                if (np) {
                    f4 a = *(const f4*)(np + j * 8);
                    f4 b = *(const f4*)(np + j * 8 + 4);
                    v[0] = f2bf(a[0]); v[1] = f2bf(a[1]); v[2] = f2bf(a[2]); v[3] = f2bf(a[3]);
                    v[4] = f2bf(b[0]); v[5] = f2bf(b[1]); v[6] = f2bf(b[2]); v[7] = f2bf(b[3]);
                } else {
                    v = (short8)0;
                }
                int cc   = half * 16 + (t & 1) * 8 + j;       // 8-elem chunk idx 0..31
                int scol = (cc * 8) ^ ((e & 7) << 3);
                *(short8*)&feat[e * 256 + scol] = v;
            }
        }
        __syncthreads();

        // ---- L1: 256 -> 128, relu ----
        {
            f32x4 acc[2][4];
#pragma unroll
            for (int mt = 0; mt < 2; ++mt) {
                f32x4 bia;
#pragma unroll
                for (int r = 0; r < 4; ++r) bia[r] = sw[w * 32 + mt * 16 + lg * 4 + r];
#pragma unroll
                for (int nt = 0; nt < 4; ++nt) acc[mt][nt] = bia;
            }
#pragma unroll
            for (int kt = 0; kt < 8; ++kt) {
                short8 bf[4];
#pragma unroll
                for (int nt = 0; nt < 4; ++nt) {
                    int e = nt * 16 + lr;
                    int k = kt * 32 + lg * 8;
                    int scol = k ^ ((e & 7) << 3);
                    bf[nt] = *(const short8*)&feat[e * 256 + scol];
                }
#pragma unroll
                for (int mt = 0; mt < 2; ++mt)
#pragma unroll
                    for (int nt = 0; nt < 4; ++nt)
                        acc[mt][nt] = MFMA16(w1f[mt][kt], bf[nt], acc[mt][nt]);
            }
#pragma unroll
            for (int mt = 0; mt < 2; ++mt)
#pragma unroll
                for (int nt = 0; nt < 4; ++nt) {
                    int e  = nt * 16 + lr;
                    int n0 = w * 32 + mt * 16 + lg * 4;
                    short4v s;
#pragma unroll
                    for (int r = 0; r < 4; ++r) {
                        float v = acc[mt][nt][r];
                        s[r] = f2bf(v > 0.0f ? v : 0.0f);
                    }
                    int scol = n0 ^ ((e & 7) << 3);
                    *(short4v*)&act1[e * 128 + scol] = s;
                }
        }
        __syncthreads();   // act1 ready; feat region now dead -> act2/act3 may use it

        // ---- L2: 128 -> 64, relu ----
        {
            f32x4 acc[4];
            f32x4 bia;
#pragma unroll
            for (int r = 0; r < 4; ++r) bia[r] = sw[128 + w * 16 + lg * 4 + r];
#pragma unroll
            for (int nt = 0; nt < 4; ++nt) acc[nt] = bia;
#pragma unroll
            for (int kt = 0; kt < 4; ++kt) {
#pragma unroll
                for (int nt = 0; nt < 4; ++nt) {
                    int e = nt * 16 + lr;
                    int k = kt * 32 + lg * 8;
                    int scol = k ^ ((e & 7) << 3);
                    short8 bf = *(const short8*)&act1[e * 128 + scol];
                    acc[nt] = MFMA16(w2f[kt], bf, acc[nt]);
                }
            }
#pragma unroll
            for (int nt = 0; nt < 4; ++nt) {
                int e  = nt * 16 + lr;
                int n0 = w * 16 + lg * 4;
                short4v s;
#pragma unroll
                for (int r = 0; r < 4; ++r) {
                    float v = acc[nt][r];
                    s[r] = f2bf(v > 0.0f ? v : 0.0f);
                }
                int scol = n0 ^ ((e & 7) << 3);
                *(short4v*)&act2[e * 64 + scol] = s;
            }
        }
        __syncthreads();   // act2 ready

        // ---- L3: 64 -> 32, relu (wave w owns edges [w*16, w*16+16)) ----
        {
            const int e3 = w * 16 + lr;
            f32x4 acc[2];
#pragma unroll
            for (int mt = 0; mt < 2; ++mt) {
#pragma unroll
                for (int r = 0; r < 4; ++r) acc[mt][r] = sw[192 + mt * 16 + lg * 4 + r];
            }
#pragma unroll
            for (int kt = 0; kt < 2; ++kt) {
                int k = kt * 32 + lg * 8;
                int scol = k ^ ((e3 & 7) << 3);
                short8 bf = *(const short8*)&act2[e3 * 64 + scol];
#pragma unroll
                for (int mt = 0; mt < 2; ++mt)
                    acc[mt] = MFMA16(w3f[mt][kt], bf, acc[mt]);
            }
#pragma unroll
            for (int mt = 0; mt < 2; ++mt) {
                short4v s;
#pragma unroll
                for (int r = 0; r < 4; ++r) {
                    float v = acc[mt][r];
                    s[r] = f2bf(v > 0.0f ? v : 0.0f);
                }
                *(short4v*)&act3[e3 * 32 + mt * 16 + lg * 4] = s;   // unswizzled
            }

            // ---- L4: 32 -> 16, NO relu (same wave, same edges) ----
            short8 bf = *(const short8*)&act3[e3 * 32 + lg * 8];
            f32x4 a4;
#pragma unroll
            for (int r = 0; r < 4; ++r) a4[r] = sw[224 + lg * 4 + r];
            a4 = MFMA16(w4f, bf, a4);
#pragma unroll
            for (int r = 0; r < 4; ++r) act4[e3 * 17 + lg * 4 + r] = a4[r];
        }
        __syncthreads();   // act4 ready

        // ---- tail rf1/rf2 per edge (64 lanes) + y copy ----
        if (t < 64) {
            float a16[16];
#pragma unroll
            for (int f = 0; f < 16; ++f) a16[f] = act4[t * 17 + f];
            float a8[8];
#pragma unroll
            for (int o = 0; o < 8; ++o) {
                float v = sw[240 + o];
#pragma unroll
                for (int f = 0; f < 16; ++f) v += a16[f] * sw[302 + o * 16 + f];
                a8[o] = v > 0.0f ? v : 0.0f;
            }
            float a4v[4];
#pragma unroll
            for (int o = 0; o < 4; ++o) {
                float v = sw[248 + o];
#pragma unroll
                for (int f = 0; f < 8; ++f) v += a8[f] * sw[430 + o * 8 + f];
                a4v[o] = v > 0.0f ? v : 0.0f;
            }
#pragma unroll
            for (int q = 0; q < 4; ++q) act6[t * 4 + q] = a4v[q];
            int eg = base + t;
            if (eg < N_EDGES) out[(size_t)N_EDGES * N_REL + eg] = (float)y[eg];
        }
        __syncthreads();   // act6 ready

        // ---- rf3: 4 -> 50, coalesced output ----
#pragma unroll
        for (int i = 0; i < 13; ++i) {
            int idx = t + i * 256;
            if (idx < 64 * N_REL) {
                int e  = idx / N_REL;
                int r  = idx - e * N_REL;
                int eg = base + e;
                if (eg < N_EDGES) {
                    float v = sw[252 + r];
#pragma unroll
                    for (int f = 0; f < 4; ++f) v += act6[e * 4 + f] * sw[462 + r * 4 + f];
                    out[(size_t)base * N_REL + idx] = v;
                }
            }
        }
        // no barrier needed: next iteration's staging writes feat/act2/act3,
        // which nothing reads after the act4 barrier; act6 rewrite is fenced
        // by the next iteration's staging + act4 barriers.
        __syncthreads();
    }
}

extern "C" void kernel_launch(void* const* d_in, const int* in_sizes, int n_in,
                              void* d_out, int out_size, void* d_ws, size_t ws_size,
                              hipStream_t stream) {
    const float* x    = (const float*)d_in[0];
    const int*   ei   = (const int*)d_in[1];
    const int*   src  = ei;
    const int*   dst  = ei + N_EDGES;
    const int*   y    = (const int*)d_in[2];
    const float* w1_l = (const float*)d_in[3];
    const float* b1   = (const float*)d_in[4];
    const float* w1_r = (const float*)d_in[5];
    const float* w2_l = (const float*)d_in[6];
    const float* b2   = (const float*)d_in[7];
    const float* w2_r = (const float*)d_in[8];
    const float* ow1  = (const float*)d_in[9];
    const float* ob1  = (const float*)d_in[10];
    const float* ow2  = (const float*)d_in[11];
    const float* ob2  = (const float*)d_in[12];
    const float* ow3  = (const float*)d_in[13];
    const float* ob3  = (const float*)d_in[14];
    const float* ow4  = (const float*)d_in[15];
    const float* ob4  = (const float*)d_in[16];
    const float* rw1  = (const float*)d_in[17];
    const float* rb1  = (const float*)d_in[18];
    const float* rw2  = (const float*)d_in[19];
    const float* rb2  = (const float*)d_in[20];
    const float* rw3  = (const float*)d_in[21];
    const float* rb3  = (const float*)d_in[22];

    float* ws  = (float*)d_ws;
    float* cnt = ws + CNT_OFF;
    float* s1  = ws + S1_OFF;
    float* s2  = ws + S2_OFF;
    float* h1  = ws + H1_OFF;
    float* h2  = ws + H2_OFF;
    float* out = (float*)d_out;

    hipMemsetAsync(d_ws, 0, (size_t)ZERO_FLOATS * sizeof(float), stream);

    {
        int total = N_EDGES * 16;
        k_scatter1<<<(total + 255) / 256, 256, 0, stream>>>(x, src, dst, s1, cnt);
    }
    k_sage1<<<N_NODES, 64, 0, stream>>>(x, s1, cnt, w1_l, b1, w1_r, h1);
    {
        long long total = (long long)N_EDGES * 64;
        k_scatter2<<<(int)((total + 255) / 256), 256, 0, stream>>>(h1, src, dst, s2);
    }
    k_sage2<<<N_NODES, 128, 0, stream>>>(h1, s2, cnt, w2_l, b2, w2_r, h2);

    k_edge_fused<<<PBLOCKS, 256, 0, stream>>>(
        h2, src, dst, y,
        ow1, ob1, ow2, ob2, ow3, ob3, ow4, ob4,
        rw1, rb1, rw2, rb2, rw3, rb3, out);
}

// Round 3
// 479.785 us; speedup vs baseline: 20.4980x; 1.7248x over previous
//
#include <hip/hip_runtime.h>
#include <hip/hip_bf16.h>

#define N_NODES 50000
#define N_EDGES 500000
#define N_REL   50
#define NTILES  ((N_EDGES + 63) / 64)   // 7813
#define PBLOCKS 512
#define NODE_TILES ((N_NODES + 63) / 64)  // 782

// workspace layout (floats)
#define CNT_OFF 0
#define S1_OFF  (N_NODES)
#define S2_OFF  (S1_OFF + N_NODES*16)
#define ZERO_FLOATS (S2_OFF + N_NODES*64)
#define H1_OFF  ZERO_FLOATS
#define H2_OFF  (H1_OFF + N_NODES*64)

typedef short short8  __attribute__((ext_vector_type(8)));
typedef short short4v __attribute__((ext_vector_type(4)));
typedef float f32x4   __attribute__((ext_vector_type(4)));
typedef float f4      __attribute__((ext_vector_type(4)));

#define MFMA16(a,b,c) __builtin_amdgcn_mfma_f32_16x16x32_bf16((a),(b),(c),0,0,0)

__device__ __forceinline__ short f2bf(float x) {
    unsigned u = __float_as_uint(x);
    unsigned r = (u + 0x7fffu + ((u >> 16) & 1u)) >> 16;   // RNE
    return (short)r;
}

__device__ __forceinline__ short8 load_wfrag(const float* __restrict__ W, int row, int K, int k) {
    const f4* p = (const f4*)(W + (size_t)row * K + k);
    f4 a = p[0], b = p[1];
    short8 r;
    r[0] = f2bf(a[0]); r[1] = f2bf(a[1]); r[2] = f2bf(a[2]); r[3] = f2bf(a[3]);
    r[4] = f2bf(b[0]); r[5] = f2bf(b[1]); r[6] = f2bf(b[2]); r[7] = f2bf(b[3]);
    return r;
}

// ---------------- scatter kernels ----------------

__global__ __launch_bounds__(256) void k_scatter1(
    const float* __restrict__ x, const int* __restrict__ src,
    const int* __restrict__ dst, float* __restrict__ s1, float* __restrict__ cnt)
{
    int t = blockIdx.x * blockDim.x + threadIdx.x;
    if (t >= N_EDGES * 16) return;
    int e = t >> 4, f = t & 15;
    int s = src[e], d = dst[e];
    atomicAdd(&s1[d * 16 + f], x[s * 16 + f]);
    if (f == 0) atomicAdd(&cnt[d], 1.0f);
}

__global__ __launch_bounds__(256) void k_scatter2(
    const float* __restrict__ h1, const int* __restrict__ src,
    const int* __restrict__ dst, float* __restrict__ s2)
{
    long long t = (long long)blockIdx.x * blockDim.x + threadIdx.x;
    if (t >= (long long)N_EDGES * 64) return;
    int e = (int)(t >> 6), f = (int)(t & 63);
    atomicAdd(&s2[(long long)dst[e] * 64 + f], h1[(long long)src[e] * 64 + f]);
}

// ---------------- SAGE1 via MFMA: [64 nodes] x K=32 (mean||x) -> 64 outs ----
// D[out][node]; A = W1cat (k<16: w1_l, k>=16: w1_r); B = feat tile.
// feat LDS: [64 rows][40 shorts] (pad 8 -> 2-way banks, free)
__global__ __launch_bounds__(256) void k_sage1_mfma(
    const float* __restrict__ x, const float* __restrict__ s1,
    const float* __restrict__ cnt,
    const float* __restrict__ w1_l, const float* __restrict__ b1,
    const float* __restrict__ w1_r, float* __restrict__ h1)
{
    __shared__ short feat[64 * 40];

    const int t    = threadIdx.x;
    const int w    = t >> 6;
    const int lane = t & 63;
    const int lr   = lane & 15;
    const int lg   = lane >> 4;
    const int base = blockIdx.x * 64;

    // A-frag: wave w owns out rows [w*16, w*16+16)
    short8 w1f;
    if (lg < 2) w1f = load_wfrag(w1_l, w * 16 + lr, 16, lg * 8);
    else        w1f = load_wfrag(w1_r, w * 16 + lr, 16, (lg - 2) * 8);

    // stage: thread t -> node-local e = t>>2, quarter q = t&3 (8 feats each)
    {
        int e  = t >> 2, q = t & 3;
        int ng = base + e;
        short8 v = (short8)0;
        if (ng < N_NODES) {
            if (q < 2) {
                float c = cnt[ng];
                c = c < 1.0f ? 1.0f : c;
                float inv = 1.0f / c;
                f4 a = *(const f4*)(s1 + (size_t)ng * 16 + q * 8);
                f4 b = *(const f4*)(s1 + (size_t)ng * 16 + q * 8 + 4);
#pragma unroll
                for (int j = 0; j < 4; ++j) { v[j] = f2bf(a[j] * inv); v[4 + j] = f2bf(b[j] * inv); }
            } else {
                f4 a = *(const f4*)(x + (size_t)ng * 16 + (q - 2) * 8);
                f4 b = *(const f4*)(x + (size_t)ng * 16 + (q - 2) * 8 + 4);
#pragma unroll
                for (int j = 0; j < 4; ++j) { v[j] = f2bf(a[j]); v[4 + j] = f2bf(b[j]); }
            }
        }
        *(short8*)&feat[e * 40 + q * 8] = v;
    }
    __syncthreads();

    f32x4 acc[4];
    f4 bia = *(const f4*)&b1[w * 16 + lg * 4];
#pragma unroll
    for (int nt = 0; nt < 4; ++nt) {
        acc[nt][0] = bia[0]; acc[nt][1] = bia[1]; acc[nt][2] = bia[2]; acc[nt][3] = bia[3];
    }
#pragma unroll
    for (int nt = 0; nt < 4; ++nt) {
        int e = nt * 16 + lr;
        short8 bf = *(const short8*)&feat[e * 40 + lg * 8];
        acc[nt] = MFMA16(w1f, bf, acc[nt]);
    }
#pragma unroll
    for (int nt = 0; nt < 4; ++nt) {
        int ng = base + nt * 16 + lr;
        if (ng < N_NODES) {
            f4 o;
#pragma unroll
            for (int r = 0; r < 4; ++r) { float v = acc[nt][r]; o[r] = v > 0.0f ? v : 0.0f; }
            *(f4*)&h1[(size_t)ng * 64 + w * 16 + lg * 4] = o;
        }
    }
}

// ---------------- SAGE2 via MFMA: [64 nodes] x K=128 (h1||mean) -> 128 outs --
// A rows: k<64 -> w2_r, k>=64 -> w2_l. feat LDS: [64][128] bf16, XOR swizzle
// scol = k ^ ((e&7)<<3)  (same proven pattern as edge kernel act1).
__global__ __launch_bounds__(256) void k_sage2_mfma(
    const float* __restrict__ h1, const float* __restrict__ s2,
    const float* __restrict__ cnt,
    const float* __restrict__ w2_l, const float* __restrict__ b2,
    const float* __restrict__ w2_r, float* __restrict__ h2)
{
    __shared__ short feat[64 * 128];

    const int t    = threadIdx.x;
    const int w    = t >> 6;
    const int lane = t & 63;
    const int lr   = lane & 15;
    const int lg   = lane >> 4;
    const int base = blockIdx.x * 64;

    // A-frags: wave w owns out rows [w*32, w*32+32)
    short8 wf[2][4];
#pragma unroll
    for (int mt = 0; mt < 2; ++mt)
#pragma unroll
        for (int kt = 0; kt < 4; ++kt) {
            int row = w * 32 + mt * 16 + lr;
            int k   = kt * 32 + lg * 8;
            wf[mt][kt] = (k < 64) ? load_wfrag(w2_r, row, 64, k)
                                  : load_wfrag(w2_l, row, 64, k - 64);
        }

    // stage: thread t -> e = t>>2, quarter q = t&3 (32 feats each)
    {
        int e  = t >> 2, q = t & 3;
        int ng = base + e;
        float inv = 1.0f;
        const float* srcp = nullptr;
        if (ng < N_NODES) {
            if (q < 2) {
                srcp = h1 + (size_t)ng * 64 + q * 32;
            } else {
                float c = cnt[ng];
                c = c < 1.0f ? 1.0f : c;
                inv = 1.0f / c;
                srcp = s2 + (size_t)ng * 64 + (q - 2) * 32;
            }
        }
#pragma unroll
        for (int j = 0; j < 4; ++j) {
            short8 v = (short8)0;
            if (srcp) {
                f4 a = *(const f4*)(srcp + j * 8);
                f4 b = *(const f4*)(srcp + j * 8 + 4);
#pragma unroll
                for (int q2 = 0; q2 < 4; ++q2) { v[q2] = f2bf(a[q2] * inv); v[4 + q2] = f2bf(b[q2] * inv); }
            }
            int cc   = q * 4 + j;                       // chunk 0..15
            int scol = (cc * 8) ^ ((e & 7) << 3);
            *(short8*)&feat[e * 128 + scol] = v;
        }
    }
    __syncthreads();

    f32x4 acc[2][4];
#pragma unroll
    for (int mt = 0; mt < 2; ++mt) {
        f4 bia = *(const f4*)&b2[w * 32 + mt * 16 + lg * 4];
#pragma unroll
        for (int nt = 0; nt < 4; ++nt) {
            acc[mt][nt][0] = bia[0]; acc[mt][nt][1] = bia[1];
            acc[mt][nt][2] = bia[2]; acc[mt][nt][3] = bia[3];
        }
    }
#pragma unroll
    for (int kt = 0; kt < 4; ++kt) {
        short8 bf[4];
#pragma unroll
        for (int nt = 0; nt < 4; ++nt) {
            int e = nt * 16 + lr;
            int k = kt * 32 + lg * 8;
            int scol = k ^ ((e & 7) << 3);
            bf[nt] = *(const short8*)&feat[e * 128 + scol];
        }
#pragma unroll
        for (int mt = 0; mt < 2; ++mt)
#pragma unroll
            for (int nt = 0; nt < 4; ++nt)
                acc[mt][nt] = MFMA16(wf[mt][kt], bf[nt], acc[mt][nt]);
    }
#pragma unroll
    for (int mt = 0; mt < 2; ++mt)
#pragma unroll
        for (int nt = 0; nt < 4; ++nt) {
            int ng = base + nt * 16 + lr;
            if (ng < N_NODES) {
                f4 o;
#pragma unroll
                for (int r = 0; r < 4; ++r) { float v = acc[mt][nt][r]; o[r] = v > 0.0f ? v : 0.0f; }
                *(f4*)&h2[(size_t)ng * 128 + w * 32 + mt * 16 + lg * 4] = o;
            }
        }
}

// ---------------- fused edge MLP (unchanged from round 1) ----------------
__global__ __launch_bounds__(256, 2) void k_edge_fused(
    const float* __restrict__ h2, const int* __restrict__ src,
    const int* __restrict__ dst, const int* __restrict__ y,
    const float* __restrict__ ow1, const float* __restrict__ ob1,
    const float* __restrict__ ow2, const float* __restrict__ ob2,
    const float* __restrict__ ow3, const float* __restrict__ ob3,
    const float* __restrict__ ow4, const float* __restrict__ ob4,
    const float* __restrict__ rw1, const float* __restrict__ rb1,
    const float* __restrict__ rw2, const float* __restrict__ rb2,
    const float* __restrict__ rw3, const float* __restrict__ rb3,
    float* __restrict__ out)
{
    __shared__ short feat[64 * 256];
    __shared__ short act1[64 * 128];
    __shared__ float act4[64 * 17];
    __shared__ float act6[64 * 4];
    __shared__ float sw[662];

    short* act2 = feat;
    short* act3 = feat + 64 * 64;

    const int t    = threadIdx.x;
    const int w    = t >> 6;
    const int lane = t & 63;
    const int lr   = lane & 15;
    const int lg   = lane >> 4;

    if (t < 128) sw[t]       = ob1[t];
    if (t < 64)  sw[128 + t] = ob2[t];
    if (t < 32)  sw[192 + t] = ob3[t];
    if (t < 16)  sw[224 + t] = ob4[t];
    if (t < 8)   sw[240 + t] = rb1[t];
    if (t < 4)   sw[248 + t] = rb2[t];
    if (t < 50)  sw[252 + t] = rb3[t];
    if (t < 128) sw[302 + t] = rw1[t];
    if (t < 32)  sw[430 + t] = rw2[t];
    if (t < 200) sw[462 + t] = rw3[t];

    short8 w1f[2][8];
#pragma unroll
    for (int mt = 0; mt < 2; ++mt)
#pragma unroll
        for (int kt = 0; kt < 8; ++kt)
            w1f[mt][kt] = load_wfrag(ow1, w * 32 + mt * 16 + lr, 256, kt * 32 + lg * 8);

    short8 w2f[4];
#pragma unroll
    for (int kt = 0; kt < 4; ++kt)
        w2f[kt] = load_wfrag(ow2, w * 16 + lr, 128, kt * 32 + lg * 8);

    short8 w3f[2][2];
#pragma unroll
    for (int mt = 0; mt < 2; ++mt)
#pragma unroll
        for (int kt = 0; kt < 2; ++kt)
            w3f[mt][kt] = load_wfrag(ow3, mt * 16 + lr, 64, kt * 32 + lg * 8);

    short8 w4f = load_wfrag(ow4, lr, 32, lg * 8);

    for (int tile = blockIdx.x; tile < NTILES; tile += PBLOCKS) {
        const int base = tile * 64;

        {
            int e    = t >> 2;
            int half = (t >> 1) & 1;
            int eg   = base + e;
            const float* np = nullptr;
            if (eg < N_EDGES) {
                int node = half ? dst[eg] : src[eg];
                np = h2 + (size_t)node * 128 + (t & 1) * 64;
            }
#pragma unroll
            for (int j = 0; j < 8; ++j) {
                short8 v;
                if (np) {
                    f4 a = *(const f4*)(np + j * 8);
                    f4 b = *(const f4*)(np + j * 8 + 4);
                    v[0] = f2bf(a[0]); v[1] = f2bf(a[1]); v[2] = f2bf(a[2]); v[3] = f2bf(a[3]);
                    v[4] = f2bf(b[0]); v[5] = f2bf(b[1]); v[6] = f2bf(b[2]); v[7] = f2bf(b[3]);
                } else {
                    v = (short8)0;
                }
                int cc   = half * 16 + (t & 1) * 8 + j;
                int scol = (cc * 8) ^ ((e & 7) << 3);
                *(short8*)&feat[e * 256 + scol] = v;
            }
        }
        __syncthreads();

        {
            f32x4 acc[2][4];
#pragma unroll
            for (int mt = 0; mt < 2; ++mt) {
                f32x4 bia;
#pragma unroll
                for (int r = 0; r < 4; ++r) bia[r] = sw[w * 32 + mt * 16 + lg * 4 + r];
#pragma unroll
                for (int nt = 0; nt < 4; ++nt) acc[mt][nt] = bia;
            }
#pragma unroll
            for (int kt = 0; kt < 8; ++kt) {
                short8 bf[4];
#pragma unroll
                for (int nt = 0; nt < 4; ++nt) {
                    int e = nt * 16 + lr;
                    int k = kt * 32 + lg * 8;
                    int scol = k ^ ((e & 7) << 3);
                    bf[nt] = *(const short8*)&feat[e * 256 + scol];
                }
#pragma unroll
                for (int mt = 0; mt < 2; ++mt)
#pragma unroll
                    for (int nt = 0; nt < 4; ++nt)
                        acc[mt][nt] = MFMA16(w1f[mt][kt], bf[nt], acc[mt][nt]);
            }
#pragma unroll
            for (int mt = 0; mt < 2; ++mt)
#pragma unroll
                for (int nt = 0; nt < 4; ++nt) {
                    int e  = nt * 16 + lr;
                    int n0 = w * 32 + mt * 16 + lg * 4;
                    short4v s;
#pragma unroll
                    for (int r = 0; r < 4; ++r) {
                        float v = acc[mt][nt][r];
                        s[r] = f2bf(v > 0.0f ? v : 0.0f);
                    }
                    int scol = n0 ^ ((e & 7) << 3);
                    *(short4v*)&act1[e * 128 + scol] = s;
                }
        }
        __syncthreads();

        {
            f32x4 acc[4];
            f32x4 bia;
#pragma unroll
            for (int r = 0; r < 4; ++r) bia[r] = sw[128 + w * 16 + lg * 4 + r];
#pragma unroll
            for (int nt = 0; nt < 4; ++nt) acc[nt] = bia;
#pragma unroll
            for (int kt = 0; kt < 4; ++kt) {
#pragma unroll
                for (int nt = 0; nt < 4; ++nt) {
                    int e = nt * 16 + lr;
                    int k = kt * 32 + lg * 8;
                    int scol = k ^ ((e & 7) << 3);
                    short8 bf = *(const short8*)&act1[e * 128 + scol];
                    acc[nt] = MFMA16(w2f[kt], bf, acc[nt]);
                }
            }
#pragma unroll
            for (int nt = 0; nt < 4; ++nt) {
                int e  = nt * 16 + lr;
                int n0 = w * 16 + lg * 4;
                short4v s;
#pragma unroll
                for (int r = 0; r < 4; ++r) {
                    float v = acc[nt][r];
                    s[r] = f2bf(v > 0.0f ? v : 0.0f);
                }
                int scol = n0 ^ ((e & 7) << 3);
                *(short4v*)&act2[e * 64 + scol] = s;
            }
        }
        __syncthreads();

        {
            const int e3 = w * 16 + lr;
            f32x4 acc[2];
#pragma unroll
            for (int mt = 0; mt < 2; ++mt) {
#pragma unroll
                for (int r = 0; r < 4; ++r) acc[mt][r] = sw[192 + mt * 16 + lg * 4 + r];
            }
#pragma unroll
            for (int kt = 0; kt < 2; ++kt) {
                int k = kt * 32 + lg * 8;
                int scol = k ^ ((e3 & 7) << 3);
                short8 bf = *(const short8*)&act2[e3 * 64 + scol];
#pragma unroll
                for (int mt = 0; mt < 2; ++mt)
                    acc[mt] = MFMA16(w3f[mt][kt], bf, acc[mt]);
            }
#pragma unroll
            for (int mt = 0; mt < 2; ++mt) {
                short4v s;
#pragma unroll
                for (int r = 0; r < 4; ++r) {
                    float v = acc[mt][r];
                    s[r] = f2bf(v > 0.0f ? v : 0.0f);
                }
                *(short4v*)&act3[e3 * 32 + mt * 16 + lg * 4] = s;
            }

            short8 bf = *(const short8*)&act3[e3 * 32 + lg * 8];
            f32x4 a4;
#pragma unroll
            for (int r = 0; r < 4; ++r) a4[r] = sw[224 + lg * 4 + r];
            a4 = MFMA16(w4f, bf, a4);
#pragma unroll
            for (int r = 0; r < 4; ++r) act4[e3 * 17 + lg * 4 + r] = a4[r];
        }
        __syncthreads();

        if (t < 64) {
            float a16[16];
#pragma unroll
            for (int f = 0; f < 16; ++f) a16[f] = act4[t * 17 + f];
            float a8[8];
#pragma unroll
            for (int o = 0; o < 8; ++o) {
                float v = sw[240 + o];
#pragma unroll
                for (int f = 0; f < 16; ++f) v += a16[f] * sw[302 + o * 16 + f];
                a8[o] = v > 0.0f ? v : 0.0f;
            }
            float a4v[4];
#pragma unroll
            for (int o = 0; o < 4; ++o) {
                float v = sw[248 + o];
#pragma unroll
                for (int f = 0; f < 8; ++f) v += a8[f] * sw[430 + o * 8 + f];
                a4v[o] = v > 0.0f ? v : 0.0f;
            }
#pragma unroll
            for (int q = 0; q < 4; ++q) act6[t * 4 + q] = a4v[q];
            int eg = base + t;
            if (eg < N_EDGES) out[(size_t)N_EDGES * N_REL + eg] = (float)y[eg];
        }
        __syncthreads();

#pragma unroll
        for (int i = 0; i < 13; ++i) {
            int idx = t + i * 256;
            if (idx < 64 * N_REL) {
                int e  = idx / N_REL;
                int r  = idx - e * N_REL;
                int eg = base + e;
                if (eg < N_EDGES) {
                    float v = sw[252 + r];
#pragma unroll
                    for (int f = 0; f < 4; ++f) v += act6[e * 4 + f] * sw[462 + r * 4 + f];
                    out[(size_t)base * N_REL + idx] = v;
                }
            }
        }
        __syncthreads();
    }
}

extern "C" void kernel_launch(void* const* d_in, const int* in_sizes, int n_in,
                              void* d_out, int out_size, void* d_ws, size_t ws_size,
                              hipStream_t stream) {
    const float* x    = (const float*)d_in[0];
    const int*   ei   = (const int*)d_in[1];
    const int*   src  = ei;
    const int*   dst  = ei + N_EDGES;
    const int*   y    = (const int*)d_in[2];
    const float* w1_l = (const float*)d_in[3];
    const float* b1   = (const float*)d_in[4];
    const float* w1_r = (const float*)d_in[5];
    const float* w2_l = (const float*)d_in[6];
    const float* b2   = (const float*)d_in[7];
    const float* w2_r = (const float*)d_in[8];
    const float* ow1  = (const float*)d_in[9];
    const float* ob1  = (const float*)d_in[10];
    const float* ow2  = (const float*)d_in[11];
    const float* ob2  = (const float*)d_in[12];
    const float* ow3  = (const float*)d_in[13];
    const float* ob3  = (const float*)d_in[14];
    const float* ow4  = (const float*)d_in[15];
    const float* ob4  = (const float*)d_in[16];
    const float* rw1  = (const float*)d_in[17];
    const float* rb1  = (const float*)d_in[18];
    const float* rw2  = (const float*)d_in[19];
    const float* rb2  = (const float*)d_in[20];
    const float* rw3  = (const float*)d_in[21];
    const float* rb3  = (const float*)d_in[22];

    float* ws  = (float*)d_ws;
    float* cnt = ws + CNT_OFF;
    float* s1  = ws + S1_OFF;
    float* s2  = ws + S2_OFF;
    float* h1  = ws + H1_OFF;
    float* h2  = ws + H2_OFF;
    float* out = (float*)d_out;

    hipMemsetAsync(d_ws, 0, (size_t)ZERO_FLOATS * sizeof(float), stream);

    {
        int total = N_EDGES * 16;
        k_scatter1<<<(total + 255) / 256, 256, 0, stream>>>(x, src, dst, s1, cnt);
    }
    k_sage1_mfma<<<NODE_TILES, 256, 0, stream>>>(x, s1, cnt, w1_l, b1, w1_r, h1);
    {
        long long total = (long long)N_EDGES * 64;
        k_scatter2<<<(int)((total + 255) / 256), 256, 0, stream>>>(h1, src, dst, s2);
    }
    k_sage2_mfma<<<NODE_TILES, 256, 0, stream>>>(h1, s2, cnt, w2_l, b2, w2_r, h2);

    k_edge_fused<<<PBLOCKS, 256, 0, stream>>>(
        h2, src, dst, y,
        ow1, ob1, ow2, ob2, ow3, ob3, ow4, ob4,
        rw1, rb1, rw2, rb2, rw3, rb3, out);
}